// Round 4
// baseline (7737.502 us; speedup 1.0000x reference)
//
#include <hip/hip_runtime.h>
#include <hip/hip_bf16.h>

// Decoder: T=50 steps, B=64, S=400, V=50000, D=E=H=A=512, POOL=2.
// R4: graph multi-kernel, 2 kernels/step: k_gru_mfma (8 blk) + k_att (64 blk, per-b
// fused q/energy/softmax/coverage/context).

#define T_STEPS 50
#define BB 64
#define SS 400

// output offsets (floats)
#define O_GOUT 0
#define O_HID 819200
#define O_ATTN_LAST 851968
#define O_CTXF 877568
#define O_PG 910336
#define O_GATTN 913536
#define O_COVL 2193536
#define O_COVF 2196736

typedef __attribute__((ext_vector_type(4))) float f4;
typedef __attribute__((ext_vector_type(8))) short s8v;

static __device__ __forceinline__ float bf2f(unsigned short u){
  unsigned v = ((unsigned)u) << 16; return __builtin_bit_cast(float, v);
}
static __device__ __forceinline__ unsigned short f2bf(float f){
  unsigned u = __builtin_bit_cast(unsigned, f);
  unsigned r = (u + 0x7FFFu + ((u >> 16) & 1u)) >> 16;
  return (unsigned short)r;
}
static __device__ __forceinline__ float sigmoidf_(float x){ return 1.f/(1.f+__expf(-x)); }
static __device__ __forceinline__ float tanhf_(float x){ float e=__expf(2.f*x); return 1.f - 2.f/(e+1.f); }

// ---------------- converts ----------------
__global__ void conv_ctx(const float* __restrict__ ctx, unsigned short* __restrict__ out){
  int o = blockIdx.x*256 + threadIdx.x;           // [S][B][E] -> [B][S][E] bf16
  if(o >= SS*BB*512) return;
  int e = o & 511; int b = (o>>9)&63; int s = o>>15;
  out[((b*SS+s)<<9) + e] = f2bf(ctx[o]);
}
__global__ void conv_emb(const int* __restrict__ y, const float* __restrict__ embW,
                         unsigned short* __restrict__ embU){
  int o = blockIdx.x*256+threadIdx.x; if(o>=T_STEPS*BB*512) return;
  int d = o & 511; int i = o>>9;
  embU[o] = f2bf(embW[(long)y[i]*512 + d]);
}
__global__ void conv_wihd(const float* __restrict__ W_ih, unsigned short* __restrict__ out){
  int o = blockIdx.x*256+threadIdx.x; if(o>=1536*512) return;
  int j = o>>9; int d = o&511;
  out[o] = f2bf(W_ih[(long)j*1024 + d]);           // D-part for gi_emb precompute
}
__global__ void conv_preT(const float* __restrict__ W_pre, unsigned short* __restrict__ out){
  int o = blockIdx.x*256+threadIdx.x; if(o>=512*512) return;
  int a = o>>9; int e = o&511;
  out[o] = f2bf(W_pre[(long)e*512 + a]);     // out[a][e]
}
__global__ void conv_roT(const float* __restrict__ W_ro, unsigned short* __restrict__ out){
  int o = blockIdx.x*256+threadIdx.x; if(o>=512*2048) return;
  int n = o>>11; int k = o&2047;
  out[o] = f2bf(W_ro[(long)k*512 + n]);      // out[n][k]
}
// pack GRU weights fragment-ordered (R2-verified): rg = blk*24 + w*6 + g*2+op
__global__ void conv_wgru(const float* __restrict__ W_ih, const float* __restrict__ W_hh,
                          unsigned short* __restrict__ Wp){
  int o = blockIdx.x*256+threadIdx.x; if(o >= 192*8192) return;
  int rg = o >> 13; int rem = o & 8191;
  int ki = rem >> 9; int ln = (rem >> 3) & 63; int e = o & 7;
  int blk = rg/24; int r2 = rg%24; int w = r2/6; int r3 = r2%6; int g = r3>>1; int op = r3&1;
  int rl = ln & 15; int kk = ((ln>>4)<<3) + e;
  int d = blk*64 + w*16 + rl; int j = g*512 + d; int k = ki*32 + kk;
  float v = op ? W_hh[(long)j*512 + k] : W_ih[(long)j*1024 + 512 + k];
  Wp[o] = f2bf(v);
}
// W_q h-part transposed row-major by n: wqh[n][k] = W_q[k][n], k<512
__global__ void conv_wqh(const float* __restrict__ W_q, unsigned short* __restrict__ out){
  int o = blockIdx.x*256+threadIdx.x; if(o>=262144) return;
  int n = o>>9; int k = o&511;
  out[o] = f2bf(W_q[(long)k*512 + n]);
}
__global__ void k_init(const float* __restrict__ hidden, const float* __restrict__ init_att,
                       const float* __restrict__ gctx, const float* __restrict__ coverage,
                       float* __restrict__ hrow0, unsigned short* __restrict__ h0bf_init,
                       unsigned short* __restrict__ ctx0bf,
                       float* __restrict__ gctxT, float* __restrict__ cov){
  int o = blockIdx.x*256+threadIdx.x;
  if(o < 32768){ float v = hidden[o]; hrow0[o] = v; h0bf_init[o] = f2bf(v); }
  else if(o < 65536){ int p=o-32768; ctx0bf[p] = f2bf(init_att[p]); }
  else if(o < 98304){ int p=o-65536; int b=p>>9,e=p&511; gctxT[e*64+b]=gctx[p]; }
  else if(o < 98304+25600){ int p=o-98304; cov[p]=coverage[p]; }
}

// ---------------- MFMA GEMM: C[M][N] = A[M][K](bf16,row-major) * B[N][Ktot](bf16,n-major)^T ----------
template<int OUT_BF16, int ACCUM>
__global__ __launch_bounds__(256) void mfma_gemm(
    const unsigned short* __restrict__ Abf, int lda,
    const unsigned short* __restrict__ Bbf, int ldb, int koff,
    void* __restrict__ Cp, int ldc, const float* __restrict__ bias, int K)
{
  __shared__ __align__(16) unsigned short Ash[128*40];
  __shared__ __align__(16) unsigned short Bsh[128*40];
  int m0 = blockIdx.x*128, n0 = blockIdx.y*128;
  int tid = threadIdx.x;
  int wid = tid>>6, lane = tid&63;
  int wm = wid>>1, wn = wid&1;
  int lr = lane&15, lg = lane>>4;
  f4 acc[4][4];
  #pragma unroll
  for(int i=0;i<4;i++)
    #pragma unroll
    for(int j=0;j<4;j++) acc[i][j]=(f4)0.f;

  for(int kt=0; kt<K; kt+=32){
    #pragma unroll
    for(int c=0;c<2;c++){
      int flat = tid*16 + c*8;
      int row = flat>>5, col = flat&31;
      const unsigned short* ga = Abf + (long)(m0+row)*lda + kt + col;
      *(uint4*)(&Ash[row*40+col]) = *(const uint4*)ga;
      const unsigned short* gb = Bbf + (long)(n0+row)*ldb + koff + kt + col;
      *(uint4*)(&Bsh[row*40+col]) = *(const uint4*)gb;
    }
    __syncthreads();
    s8v av[4], bv[4];
    #pragma unroll
    for(int mi=0;mi<4;mi++) av[mi] = *(const s8v*)(&Ash[(wm*64+mi*16+lr)*40 + lg*8]);
    #pragma unroll
    for(int ni=0;ni<4;ni++) bv[ni] = *(const s8v*)(&Bsh[(wn*64+ni*16+lr)*40 + lg*8]);
    #pragma unroll
    for(int mi=0;mi<4;mi++)
      #pragma unroll
      for(int ni=0;ni<4;ni++)
        acc[mi][ni] = __builtin_amdgcn_mfma_f32_16x16x32_bf16(av[mi], bv[ni], acc[mi][ni], 0,0,0);
    __syncthreads();
  }
  #pragma unroll
  for(int mi=0;mi<4;mi++)
    #pragma unroll
    for(int ni=0;ni<4;ni++){
      int gc = n0 + wn*64 + ni*16 + lr;
      #pragma unroll
      for(int r=0;r<4;r++){
        int gr = m0 + wm*64 + mi*16 + lg*4 + r;
        float v = acc[mi][ni][r];
        if(bias) v += bias[gc];
        if(OUT_BF16){
          ((unsigned short*)Cp)[(long)gr*ldc + gc] = f2bf(v);
        } else {
          float* C = (float*)Cp;
          if(ACCUM) v += C[(long)gr*ldc+gc];
          C[(long)gr*ldc+gc] = v;
        }
      }
    }
}

// ---------------- small fp32 GEMM (one-time precompute only) ----------------
__global__ __launch_bounds__(256) void small_gemm_kn(
  const float* __restrict__ AT, const float* __restrict__ W, int koff, int N,
  const float* __restrict__ addend, float* __restrict__ out, int K)
{
  int tid = threadIdx.x;
  int b = tid&63; int nq = tid>>6;
  int n = __builtin_amdgcn_readfirstlane(blockIdx.x*4 + nq);
  float acc = addend ? addend[b*N+n] : 0.f;
  const float* wp = W + (long)koff*N + n;
  #pragma unroll 8
  for(int k=0;k<512;k++){
    acc = fmaf(AT[k*64+b], wp[(long)k*N], acc);
  }
  (void)K;
  out[b*N+n] = acc;
}

// ---------------- MFMA GRU step (R2-verified) ----------------
__global__ __launch_bounds__(256) void k_gru_mfma(
  const unsigned short* __restrict__ ctxprev, const unsigned short* __restrict__ hprevbf,
  const float* __restrict__ hrow_in, float* __restrict__ hrow_out,
  const unsigned short* __restrict__ Wp, const float* __restrict__ gi_emb,
  const float* __restrict__ b_hh, unsigned short* __restrict__ h0bf_all,
  float* __restrict__ outp, int t)
{
  __shared__ __align__(16) unsigned short Ash[2*64*256];   // 64KB
  int blk = blockIdx.x;
  int tid = threadIdx.x;
  int w = tid>>6, lane = tid&63;
  int lr = lane&15, lg = lane>>4;
  int swz = (lr&7)<<4;

  f4 acc[6];
  #pragma unroll
  for(int u=0;u<6;u++) acc[u]=(f4)0.f;

  int rgbase = blk*24 + w*6;

  for(int kp=0; kp<2; kp++){
    for(int c = tid; c < 4096; c += 256){
      int op = c>>11; int row = (c>>5)&63; int kc = c&31;
      const unsigned short* src = (op ? hprevbf : ctxprev) + row*512 + kp*256 + kc*8;
      uint4 v = *(const uint4*)src;
      int dst = op*32768 + row*512 + ((kc*16) ^ ((row&7)<<4));
      *(uint4*)((char*)Ash + dst) = v;
    }
    __syncthreads();
    // note: per-wave output tile is 16 dims x 64 batch -> 4 m-frags of 16x16
    #pragma unroll 2
    for(int ktl=0; ktl<256; ktl+=32){
      int ki = kp*8 + (ktl>>5);
      s8v bv[6];
      #pragma unroll
      for(int u=0;u<6;u++)
        bv[u] = *(const s8v*)(Wp + (long)(rgbase+u)*8192 + ki*512 + lane*8);
      #pragma unroll
      for(int mi=0;mi<4;mi++){
        s8v av0 = *(const s8v*)((const char*)Ash + (mi*16+lr)*512 + ((ktl*2 + lg*16) ^ swz));
        s8v av1 = *(const s8v*)((const char*)Ash + 32768 + (mi*16+lr)*512 + ((ktl*2 + lg*16) ^ swz));
        (void)av0; (void)av1;
        // accumulate per-u but acc layout is [6] over mi?  -- restructure below
      }
      (void)bv;
      break;
    }
    __syncthreads();
    break;
  }
  // NOTE: restructured version below (kept single definition for clarity)
  // --- actual implementation ---
  // re-init
  f4 acc2[6][4];
  #pragma unroll
  for(int u=0;u<6;u++)
    #pragma unroll
    for(int mi=0;mi<4;mi++) acc2[u][mi]=(f4)0.f;
  for(int kp=0; kp<2; kp++){
    for(int c = tid; c < 4096; c += 256){
      int op = c>>11; int row = (c>>5)&63; int kc = c&31;
      const unsigned short* src = (op ? hprevbf : ctxprev) + row*512 + kp*256 + kc*8;
      uint4 v = *(const uint4*)src;
      int dst = op*32768 + row*512 + ((kc*16) ^ ((row&7)<<4));
      *(uint4*)((char*)Ash + dst) = v;
    }
    __syncthreads();
    #pragma unroll 2
    for(int ktl=0; ktl<256; ktl+=32){
      s8v av[2][4];
      #pragma unroll
      for(int op=0;op<2;op++)
        #pragma unroll
        for(int mi=0;mi<4;mi++)
          av[op][mi] = *(const s8v*)((const char*)Ash + op*32768 + (mi*16+lr)*512 + ((ktl*2 + lg*16) ^ swz));
      int ki = kp*8 + (ktl>>5);
      const unsigned short* wb = Wp + (long)rgbase*8192 + ki*512 + lane*8;
      #pragma unroll
      for(int u=0;u<6;u++){
        s8v bv = *(const s8v*)(wb + (long)u*8192);
        #pragma unroll
        for(int mi=0;mi<4;mi++)
          acc2[u][mi] = __builtin_amdgcn_mfma_f32_16x16x32_bf16(av[u&1][mi], bv, acc2[u][mi], 0,0,0);
      }
    }
    __syncthreads();
  }

  int d = blk*64 + w*16 + lr;
  float bhr = b_hh[d], bhz = b_hh[512+d], bhn = b_hh[1024+d];
  #pragma unroll
  for(int mi=0;mi<4;mi++){
    #pragma unroll
    for(int r=0;r<4;r++){
      int b = mi*16 + lg*4 + r;
      const float* ge = gi_emb + (long)(t*64+b)*1536;
      float rr = sigmoidf_(ge[d]      + bhr + acc2[0][mi][r] + acc2[1][mi][r]);
      float zz = sigmoidf_(ge[512+d]  + bhz + acc2[2][mi][r] + acc2[3][mi][r]);
      float nn = tanhf_(  ge[1024+d]        + acc2[4][mi][r] + rr*(acc2[5][mi][r] + bhn));
      float hp = hrow_in[b*512 + d];
      float hv = (1.f-zz)*nn + zz*hp;
      hrow_out[b*512+d] = hv;
      h0bf_all[(long)(t*64+b)*512 + d] = f2bf(hv);
      if(t==T_STEPS-1) outp[O_HID + b*512 + d] = hv;
    }
  }
}

// ---------------- fused per-b attention step ----------------
__global__ __launch_bounds__(256) void k_att(
  const unsigned short* __restrict__ h0bf_all,
  const unsigned short* __restrict__ wqh,
  const float* __restrict__ q_g,
  const unsigned short* __restrict__ pre,
  const unsigned short* __restrict__ ctxbf,
  const float* __restrict__ Wv, const float* __restrict__ Wcov,
  const float* __restrict__ padm,
  float* __restrict__ cov, unsigned short* __restrict__ ctx_all,
  float* __restrict__ outp, int t)
{
  __shared__ float h_sh[512];
  __shared__ float q_sh[512];
  __shared__ float wv_sh[512];
  __shared__ float wc_sh[512];
  __shared__ float sm[400];
  __shared__ float covL[400];
  __shared__ float red[256];
  __shared__ float pb[4][8][64];
  int b = blockIdx.x; int tid = threadIdx.x;
  int w = tid>>6, lane = tid&63;

  {
    unsigned hu = *(const unsigned*)(h0bf_all + (((long)(t*64+b))<<9) + tid*2);
    h_sh[tid*2]   = bf2f((unsigned short)(hu&0xffffu));
    h_sh[tid*2+1] = bf2f((unsigned short)(hu>>16));
    float2 wv2 = *(const float2*)(Wv + tid*2);
    wv_sh[tid*2]=wv2.x; wv_sh[tid*2+1]=wv2.y;
    float2 wc2 = *(const float2*)(Wcov + tid*2);
    wc_sh[tid*2]=wc2.x; wc_sh[tid*2+1]=wc2.y;
    if(tid<200){ float2 c2 = *(const float2*)(cov + b*400 + tid*2); covL[tid*2]=c2.x; covL[tid*2+1]=c2.y; }
  }
  __syncthreads();
  // q = h @ Wq(h)^T + q_g
  #pragma unroll
  for(int rep=0;rep<2;rep++){
    int n = tid + rep*256;
    float acc = q_g[b*512+n];
    const unsigned short* wr = wqh + (long)n*512;
    #pragma unroll 8
    for(int k8=0;k8<64;k8++){
      uint4 uv = *(const uint4*)(wr + k8*8);
      const unsigned* uu = (const unsigned*)&uv;
      const float* hp = h_sh + k8*8;
      #pragma unroll
      for(int q4=0;q4<4;q4++){
        acc = fmaf(bf2f((unsigned short)(uu[q4]&0xffffu)), hp[q4*2], acc);
        acc = fmaf(bf2f((unsigned short)(uu[q4]>>16)),    hp[q4*2+1], acc);
      }
    }
    q_sh[n]=acc;
  }
  __syncthreads();
  // energy (800 half-dot units)
  for(int u=tid; u<800; u+=256){
    int s = u>>1; int half = u&1; int a0 = half*256;
    float cv = covL[s];
    const unsigned short* rp = pre + (((long)(b*400+s))<<9) + a0;
    float part = 0.f;
    #pragma unroll 4
    for(int j=0;j<32;j++){
      uint4 uv = *(const uint4*)(rp + j*8);
      const unsigned* uu = (const unsigned*)&uv;
      #pragma unroll
      for(int q4=0;q4<4;q4++){
        int a = a0 + j*8 + q4*2;
        float lo = bf2f((unsigned short)(uu[q4]&0xffffu));
        float hi = bf2f((unsigned short)(uu[q4]>>16));
        part += wv_sh[a]  * tanhf_(lo + q_sh[a]   + cv*wc_sh[a]);
        part += wv_sh[a+1]* tanhf_(hi + q_sh[a+1] + cv*wc_sh[a+1]);
      }
    }
    part += __shfl_xor(part, 1, 64);
    if(half==0)
      sm[s] = (padm[b*400+s]>0.5f) ? -1e18f : part;
  }
  __syncthreads();
  // softmax over sm[400]
  float v1 = sm[tid];
  bool has2 = tid<144;
  float v2 = has2 ? sm[256+tid] : -INFINITY;
  red[tid]=fmaxf(v1,v2); __syncthreads();
  for(int o=128;o;o>>=1){ if(tid<o) red[tid]=fmaxf(red[tid],red[tid+o]); __syncthreads(); }
  float mx = red[0]; __syncthreads();
  float p1=__expf(v1-mx), p2=has2?__expf(v2-mx):0.f;
  red[tid]=p1+p2; __syncthreads();
  for(int o=128;o;o>>=1){ if(tid<o) red[tid]+=red[tid+o]; __syncthreads(); }
  float inv = 1.f/red[0]; __syncthreads();
  float a1=p1*inv, a2=p2*inv;
  sm[tid]=a1; if(has2) sm[256+tid]=a2;
  // coverage + cov_loss + gattn
  {
    float* gat = outp + O_GATTN + (long)t*25600 + b*400;
    gat[tid]=a1;
    float c1 = covL[tid];
    float cl = fminf(a1,c1);
    float nc1 = c1+a1;
    cov[b*400+tid]=nc1;
    if(t==T_STEPS-1){ outp[O_ATTN_LAST + b*400 + tid]=a1; outp[O_COVF + b*400 + tid]=nc1; }
    if(has2){
      gat[256+tid]=a2;
      float c2=covL[256+tid];
      cl += fminf(a2,c2);
      float nc2=c2+a2;
      cov[b*400+256+tid]=nc2;
      if(t==T_STEPS-1){ outp[O_ATTN_LAST + b*400+256+tid]=a2; outp[O_COVF + b*400+256+tid]=nc2; }
    }
    red[tid]=cl; __syncthreads();
    for(int o=128;o;o>>=1){ if(tid<o) red[tid]+=red[tid+o]; __syncthreads(); }
    if(tid==0) outp[O_COVL + t*64 + b]=red[0];
  }
  __syncthreads();
  // context: wave w handles s = w,w+4,..., lanes own e=lane*8..lane*8+7
  float acc8[8];
  #pragma unroll
  for(int j=0;j<8;j++) acc8[j]=0.f;
  for(int s=w; s<400; s+=4){
    float av = sm[s];
    uint4 uv = *(const uint4*)(ctxbf + (((long)(b*400+s))<<9) + lane*8);
    const unsigned* uu=(const unsigned*)&uv;
    #pragma unroll
    for(int q4=0;q4<4;q4++){
      acc8[q4*2]   = fmaf(av, bf2f((unsigned short)(uu[q4]&0xffffu)), acc8[q4*2]);
      acc8[q4*2+1] = fmaf(av, bf2f((unsigned short)(uu[q4]>>16)),    acc8[q4*2+1]);
    }
  }
  #pragma unroll
  for(int j=0;j<8;j++) pb[w][j][lane]=acc8[j];
  __syncthreads();
  #pragma unroll
  for(int rep=0;rep<2;rep++){
    int n = tid + rep*256;
    float v = pb[0][n&7][n>>3]+pb[1][n&7][n>>3]+pb[2][n&7][n>>3]+pb[3][n&7][n>>3];
    ctx_all[(((long)(t*64+b))<<9)+n]=f2bf(v);
    if(t==T_STEPS-1) outp[O_CTXF + b*512 + n]=v;
  }
}

// ---------------- post-pass ----------------
__global__ __launch_bounds__(256) void k_pgen(
  const unsigned short* __restrict__ embU, const unsigned short* __restrict__ h0bf,
  const unsigned short* __restrict__ ctxA, const float* __restrict__ Wpg,
  const float* __restrict__ bpg, float* __restrict__ outp)
{
  int wid = threadIdx.x>>6, lane=threadIdx.x&63;
  int m = blockIdx.x*4 + wid;
  float acc=0.f;
  #pragma unroll
  for(int i=0;i<8;i++){
    int k = i*64+lane;
    acc = fmaf(bf2f(ctxA[(long)m*512+k]), Wpg[k], acc);
    acc = fmaf(bf2f(h0bf[(long)m*512+k]), Wpg[512+k], acc);
    acc = fmaf(bf2f(embU[(long)m*512+k]), Wpg[1024+k], acc);
  }
  #pragma unroll
  for(int off=32; off; off>>=1) acc += __shfl_xor(acc, off, 64);
  if(lane==0) outp[O_PG + m] = sigmoidf_(acc + bpg[0]);
}

__global__ void k_maxout(const float* __restrict__ RO, const float* __restrict__ ro_g,
                         float* __restrict__ outp){
  int o = blockIdx.x*256+threadIdx.x; if(o>=819200) return;
  int h = o & 255; int m = o>>8; int b = m & 63;
  float v0 = RO[(long)m*512 + 2*h]   + ro_g[b*512 + 2*h];
  float v1 = RO[(long)m*512 + 2*h+1] + ro_g[b*512 + 2*h+1];
  outp[O_GOUT + o] = fmaxf(v0,v1);
}

extern "C" void kernel_launch(void* const* d_in, const int* in_sizes, int n_in,
                              void* d_out, int out_size, void* d_ws, size_t ws_size,
                              hipStream_t stream)
{
  (void)in_sizes; (void)n_in; (void)out_size; (void)ws_size;
  const int*   y       = (const int*)d_in[0];
  const float* hidden  = (const float*)d_in[1];
  const float* context = (const float*)d_in[2];
  const float* padm    = (const float*)d_in[3];
  const float* init_att= (const float*)d_in[4];
  const float* coverage= (const float*)d_in[5];
  const float* gctx    = (const float*)d_in[6];
  const float* embW    = (const float*)d_in[7];
  const float* W_ih    = (const float*)d_in[8];
  const float* W_hh    = (const float*)d_in[9];
  const float* b_ih    = (const float*)d_in[10];
  const float* b_hh    = (const float*)d_in[11];
  const float* W_pre   = (const float*)d_in[12];
  const float* b_pre   = (const float*)d_in[13];
  const float* W_q     = (const float*)d_in[14];
  const float* W_v     = (const float*)d_in[15];
  const float* W_cov   = (const float*)d_in[16];
  const float* W_pg    = (const float*)d_in[17];
  const float* b_pg    = (const float*)d_in[18];
  const float* W_ro    = (const float*)d_in[19];
  const float* b_ro    = (const float*)d_in[20];
  float* out = (float*)d_out;

  char* wsb = (char*)d_ws;
  size_t off = 0;
  auto alloc = [&](size_t bytes)->char*{ char* p = wsb+off; off += (bytes+255)&~255UL; return p; };
  unsigned short* pre    = (unsigned short*)alloc(25600UL*512*2);
  unsigned short* ctxbf  = (unsigned short*)alloc(13107200UL*2);
  unsigned short* embU   = (unsigned short*)alloc(3200UL*512*2);
  unsigned short* wihbf  = (unsigned short*)alloc(1536UL*512*2);
  unsigned short* wpreT  = (unsigned short*)alloc(512UL*512*2);
  unsigned short* wroT   = (unsigned short*)alloc(512UL*2048*2);
  unsigned short* Wgru   = (unsigned short*)alloc(192UL*8192*2);
  unsigned short* wqh    = (unsigned short*)alloc(512UL*512*2);
  float* gi_emb = (float*)alloc(3200UL*1536*4);
  float* RO     = (float*)alloc(3200UL*512*4);
  float* q_g    = (float*)alloc(64UL*512*4);
  float* ro_g   = (float*)alloc(64UL*512*4);
  float* hrow0  = (float*)alloc(64UL*512*4);
  float* hrow1  = (float*)alloc(64UL*512*4);
  float* gctxT  = (float*)alloc(512UL*64*4);
  unsigned short* h0bf = (unsigned short*)alloc(3200UL*512*2);
  unsigned short* h0bf_init = (unsigned short*)alloc(64UL*512*2);
  unsigned short* ctx0bf    = (unsigned short*)alloc(64UL*512*2);
  unsigned short* ctxA = (unsigned short*)alloc(3200UL*512*2);
  float* cov    = (float*)alloc(64UL*400*4);

  // converts + init
  conv_ctx <<<dim3(51200),dim3(256),0,stream>>>(context, ctxbf);
  conv_emb <<<dim3(6400), dim3(256),0,stream>>>(y, embW, embU);
  conv_wihd<<<dim3(3072), dim3(256),0,stream>>>(W_ih, wihbf);
  conv_preT<<<dim3(1024), dim3(256),0,stream>>>(W_pre, wpreT);
  conv_roT <<<dim3(4096), dim3(256),0,stream>>>(W_ro, wroT);
  conv_wgru<<<dim3(6144), dim3(256),0,stream>>>(W_ih, W_hh, Wgru);
  conv_wqh <<<dim3(1024), dim3(256),0,stream>>>(W_q, wqh);
  k_init   <<<dim3(485),  dim3(256),0,stream>>>(hidden, init_att, gctx, coverage,
                                                hrow0, h0bf_init, ctx0bf, gctxT, cov);

  // precompute GEMMs
  mfma_gemm<1,0><<<dim3(200,4),dim3(256),0,stream>>>(ctxbf,512, wpreT,512,0,  pre,   512, b_pre, 512);
  mfma_gemm<0,0><<<dim3(25,12),dim3(256),0,stream>>>(embU, 512, wihbf,512,0,  gi_emb,1536,b_ih, 512);
  mfma_gemm<0,0><<<dim3(25,4), dim3(256),0,stream>>>(embU, 512, wroT,2048,0,  RO,    512, b_ro, 512);
  small_gemm_kn<<<dim3(128),dim3(256),0,stream>>>(gctxT, W_q, 512, 512, nullptr, q_g, 512);
  small_gemm_kn<<<dim3(128),dim3(256),0,stream>>>(gctxT, W_ro,1536, 512, nullptr, ro_g, 512);

  // scan: 2 kernels/step
  for(int t=0; t<T_STEPS; t++){
    float* hin  = (t&1) ? hrow1 : hrow0;
    float* hout = (t&1) ? hrow0 : hrow1;
    const unsigned short* ctxprev = (t==0) ? ctx0bf : (ctxA + (long)(t-1)*32768);
    const unsigned short* hprevbf = (t==0) ? h0bf_init : (h0bf + (long)(t-1)*32768);
    k_gru_mfma<<<dim3(8),dim3(256),0,stream>>>(ctxprev, hprevbf, hin, hout,
                                               Wgru, gi_emb, b_hh, h0bf, out, t);
    k_att<<<dim3(64),dim3(256),0,stream>>>(h0bf, wqh, q_g, pre, ctxbf,
                                           W_v, W_cov, padm, cov, ctxA, out, t);
  }

  // post-pass
  mfma_gemm<0,1><<<dim3(25,4),dim3(256),0,stream>>>(h0bf,512, wroT,2048,512,  RO,512, nullptr, 512);
  mfma_gemm<0,1><<<dim3(25,4),dim3(256),0,stream>>>(ctxA,512, wroT,2048,1024, RO,512, nullptr, 512);
  k_pgen  <<<dim3(800), dim3(256),0,stream>>>(embU, h0bf, ctxA, W_pg, b_pg, out);
  k_maxout<<<dim3(3200),dim3(256),0,stream>>>(RO, ro_g, out);
}

// Round 5
// 3709.971 us; speedup vs baseline: 2.0856x; 2.0856x over previous
//
#include <hip/hip_runtime.h>
#include <hip/hip_bf16.h>

// Decoder: T=50 steps, B=64, S=400, V=50000, D=E=H=A=512, POOL=2.
// R5: 3 kernels/step: k_gru_mfma(+q-partials,+covl finish) -> k_energy (wave-per-row,
// nt streams) -> k_smctx (softmax+coverage+context partials). nt loads protect L2
// residency of GRU weights across steps.

#define T_STEPS 50
#define BB 64
#define SS 400

// output offsets (floats)
#define O_GOUT 0
#define O_HID 819200
#define O_ATTN_LAST 851968
#define O_CTXF 877568
#define O_PG 910336
#define O_GATTN 913536
#define O_COVL 2193536
#define O_COVF 2196736

typedef __attribute__((ext_vector_type(4))) float f4;
typedef __attribute__((ext_vector_type(8))) short s8v;
typedef __attribute__((ext_vector_type(4))) unsigned u4;

static __device__ __forceinline__ float bf2f(unsigned short u){
  unsigned v = ((unsigned)u) << 16; return __builtin_bit_cast(float, v);
}
static __device__ __forceinline__ unsigned short f2bf(float f){
  unsigned u = __builtin_bit_cast(unsigned, f);
  unsigned r = (u + 0x7FFFu + ((u >> 16) & 1u)) >> 16;
  return (unsigned short)r;
}
static __device__ __forceinline__ float sigmoidf_(float x){ return 1.f/(1.f+__expf(-x)); }
static __device__ __forceinline__ float tanhf_(float x){ float e=__expf(2.f*x); return 1.f - 2.f/(e+1.f); }
static __device__ __forceinline__ u4 ntld(const unsigned short* p){
  return __builtin_nontemporal_load((const u4*)p);
}

// ---------------- converts ----------------
__global__ void conv_ctx(const float* __restrict__ ctx, unsigned short* __restrict__ out){
  int o = blockIdx.x*256 + threadIdx.x;           // [S][B][E] -> [B][S][E] bf16
  if(o >= SS*BB*512) return;
  int e = o & 511; int b = (o>>9)&63; int s = o>>15;
  out[((b*SS+s)<<9) + e] = f2bf(ctx[o]);
}
__global__ void conv_emb(const int* __restrict__ y, const float* __restrict__ embW,
                         unsigned short* __restrict__ embU){
  int o = blockIdx.x*256+threadIdx.x; if(o>=T_STEPS*BB*512) return;
  int d = o & 511; int i = o>>9;
  embU[o] = f2bf(embW[(long)y[i]*512 + d]);
}
__global__ void conv_wihd(const float* __restrict__ W_ih, unsigned short* __restrict__ out){
  int o = blockIdx.x*256+threadIdx.x; if(o>=1536*512) return;
  int j = o>>9; int d = o&511;
  out[o] = f2bf(W_ih[(long)j*1024 + d]);           // D-part for gi_emb precompute
}
__global__ void conv_preT(const float* __restrict__ W_pre, unsigned short* __restrict__ out){
  int o = blockIdx.x*256+threadIdx.x; if(o>=512*512) return;
  int a = o>>9; int e = o&511;
  out[o] = f2bf(W_pre[(long)e*512 + a]);     // out[a][e]
}
__global__ void conv_roT(const float* __restrict__ W_ro, unsigned short* __restrict__ out){
  int o = blockIdx.x*256+threadIdx.x; if(o>=512*2048) return;
  int n = o>>11; int k = o&2047;
  out[o] = f2bf(W_ro[(long)k*512 + n]);      // out[n][k]
}
// pack GRU weights fragment-ordered: rg = blk*24 + w*6 + g*2+op
__global__ void conv_wgru(const float* __restrict__ W_ih, const float* __restrict__ W_hh,
                          unsigned short* __restrict__ Wp){
  int o = blockIdx.x*256+threadIdx.x; if(o >= 192*8192) return;
  int rg = o >> 13; int rem = o & 8191;
  int ki = rem >> 9; int ln = (rem >> 3) & 63; int e = o & 7;
  int blk = rg/24; int r2 = rg%24; int w = r2/6; int r3 = r2%6; int g = r3>>1; int op = r3&1;
  int rl = ln & 15; int kk = ((ln>>4)<<3) + e;
  int d = blk*64 + w*16 + rl; int j = g*512 + d; int k = ki*32 + kk;
  float v = op ? W_hh[(long)j*512 + k] : W_ih[(long)j*1024 + 512 + k];
  Wp[o] = f2bf(v);
}
// pack W_q(h-part) for the gru-side q MFMA: [blk 0..7][nrg 0..31][kf 0..1][ln][8]
__global__ void conv_wq3(const float* __restrict__ W_q, unsigned short* __restrict__ Wp){
  int o = blockIdx.x*256+threadIdx.x; if(o>=262144) return;
  int e = o&7; int ln=(o>>3)&63; int kf=(o>>9)&1; int nrg=(o>>10)&31; int blk=o>>15;
  int n = nrg*16 + (ln&15);
  int k = blk*64 + kf*32 + ((ln>>4)<<3) + e;
  Wp[o] = f2bf(W_q[(long)k*512 + n]);
}
__global__ void k_init(const float* __restrict__ hidden, const float* __restrict__ init_att,
                       const float* __restrict__ gctx, const float* __restrict__ coverage,
                       float* __restrict__ hrow0, unsigned short* __restrict__ h0bf_init,
                       unsigned short* __restrict__ ctx0bf,
                       float* __restrict__ gctxT, float* __restrict__ cov){
  int o = blockIdx.x*256+threadIdx.x;
  if(o < 32768){ float v = hidden[o]; hrow0[o] = v; h0bf_init[o] = f2bf(v); }
  else if(o < 65536){ int p=o-32768; ctx0bf[p] = f2bf(init_att[p]); }
  else if(o < 98304){ int p=o-65536; int b=p>>9,e=p&511; gctxT[e*64+b]=gctx[p]; }
  else if(o < 98304+25600){ int p=o-98304; cov[p]=coverage[p]; }
}

// ---------------- MFMA GEMM (precompute/post) ----------------
template<int OUT_BF16, int ACCUM>
__global__ __launch_bounds__(256) void mfma_gemm(
    const unsigned short* __restrict__ Abf, int lda,
    const unsigned short* __restrict__ Bbf, int ldb, int koff,
    void* __restrict__ Cp, int ldc, const float* __restrict__ bias, int K)
{
  __shared__ __align__(16) unsigned short Ash[128*40];
  __shared__ __align__(16) unsigned short Bsh[128*40];
  int m0 = blockIdx.x*128, n0 = blockIdx.y*128;
  int tid = threadIdx.x;
  int wid = tid>>6, lane = tid&63;
  int wm = wid>>1, wn = wid&1;
  int lr = lane&15, lg = lane>>4;
  f4 acc[4][4];
  #pragma unroll
  for(int i=0;i<4;i++)
    #pragma unroll
    for(int j=0;j<4;j++) acc[i][j]=(f4)0.f;

  for(int kt=0; kt<K; kt+=32){
    #pragma unroll
    for(int c=0;c<2;c++){
      int flat = tid*16 + c*8;
      int row = flat>>5, col = flat&31;
      const unsigned short* ga = Abf + (long)(m0+row)*lda + kt + col;
      *(uint4*)(&Ash[row*40+col]) = *(const uint4*)ga;
      const unsigned short* gb = Bbf + (long)(n0+row)*ldb + koff + kt + col;
      *(uint4*)(&Bsh[row*40+col]) = *(const uint4*)gb;
    }
    __syncthreads();
    s8v av[4], bv[4];
    #pragma unroll
    for(int mi=0;mi<4;mi++) av[mi] = *(const s8v*)(&Ash[(wm*64+mi*16+lr)*40 + lg*8]);
    #pragma unroll
    for(int ni=0;ni<4;ni++) bv[ni] = *(const s8v*)(&Bsh[(wn*64+ni*16+lr)*40 + lg*8]);
    #pragma unroll
    for(int mi=0;mi<4;mi++)
      #pragma unroll
      for(int ni=0;ni<4;ni++)
        acc[mi][ni] = __builtin_amdgcn_mfma_f32_16x16x32_bf16(av[mi], bv[ni], acc[mi][ni], 0,0,0);
    __syncthreads();
  }
  #pragma unroll
  for(int mi=0;mi<4;mi++)
    #pragma unroll
    for(int ni=0;ni<4;ni++){
      int gc = n0 + wn*64 + ni*16 + lr;
      #pragma unroll
      for(int r=0;r<4;r++){
        int gr = m0 + wm*64 + mi*16 + lg*4 + r;
        float v = acc[mi][ni][r];
        if(bias) v += bias[gc];
        if(OUT_BF16){
          ((unsigned short*)Cp)[(long)gr*ldc + gc] = f2bf(v);
        } else {
          float* C = (float*)Cp;
          if(ACCUM) v += C[(long)gr*ldc+gc];
          C[(long)gr*ldc+gc] = v;
        }
      }
    }
}

// ---------------- small fp32 GEMM (one-time precompute only) ----------------
__global__ __launch_bounds__(256) void small_gemm_kn(
  const float* __restrict__ AT, const float* __restrict__ W, int koff, int N,
  const float* __restrict__ addend, float* __restrict__ out)
{
  int tid = threadIdx.x;
  int b = tid&63; int nq = tid>>6;
  int n = __builtin_amdgcn_readfirstlane(blockIdx.x*4 + nq);
  float acc = addend ? addend[b*N+n] : 0.f;
  const float* wp = W + (long)koff*N + n;
  #pragma unroll 8
  for(int k=0;k<512;k++){
    acc = fmaf(AT[k*64+b], wp[(long)k*N], acc);
  }
  out[b*N+n] = acc;
}

// ---------------- MFMA GRU step + q-partials + covl finish ----------------
__global__ __launch_bounds__(256) void k_gru_mfma(
  const unsigned short* __restrict__ ctx0bf, const unsigned short* __restrict__ Pprev,
  const unsigned short* __restrict__ hprevbf,
  const float* __restrict__ hrow_in, float* __restrict__ hrow_out,
  const unsigned short* __restrict__ Wp, const unsigned short* __restrict__ WqP,
  const float* __restrict__ gi_emb, const float* __restrict__ b_hh,
  unsigned short* __restrict__ h0bf_all, float* __restrict__ qpart,
  const float* __restrict__ covl_part, float* __restrict__ outp, int t)
{
  __shared__ __align__(16) unsigned short Ash[2*64*256];   // 64KB per K-phase
  __shared__ __align__(16) unsigned short HS[64*72];       // h slice, padded stride
  int blk = blockIdx.x;
  int tid = threadIdx.x;
  int w = tid>>6, lane = tid&63;
  int lr = lane&15, lg = lane>>4;
  int swz = (lr&7)<<4;
  int rgbase = blk*24 + w*6;

  f4 acc2[6][4];
  #pragma unroll
  for(int u=0;u<6;u++)
    #pragma unroll
    for(int mi=0;mi<4;mi++) acc2[u][mi]=(f4)0.f;

  for(int kp=0; kp<2; kp++){
    for(int c = tid; c < 4096; c += 256){
      int op = c>>11; int row = (c>>5)&63; int kc = c&31;
      int e0 = kp*256 + kc*8;
      u4 v;
      if(op){
        v = *(const u4*)(hprevbf + row*512 + e0);
      } else if(Pprev){
        float s0=0,s1=0,s2=0,s3=0,s4=0,s5=0,s6=0,s7=0;
        #pragma unroll
        for(int p=0;p<4;p++){
          u4 pv = ntld(Pprev + ((long)p<<15) + row*512 + e0);
          s0 += bf2f((unsigned short)(pv.x&0xffffu)); s1 += bf2f((unsigned short)(pv.x>>16));
          s2 += bf2f((unsigned short)(pv.y&0xffffu)); s3 += bf2f((unsigned short)(pv.y>>16));
          s4 += bf2f((unsigned short)(pv.z&0xffffu)); s5 += bf2f((unsigned short)(pv.z>>16));
          s6 += bf2f((unsigned short)(pv.w&0xffffu)); s7 += bf2f((unsigned short)(pv.w>>16));
        }
        v.x = (unsigned)f2bf(s0) | ((unsigned)f2bf(s1)<<16);
        v.y = (unsigned)f2bf(s2) | ((unsigned)f2bf(s3)<<16);
        v.z = (unsigned)f2bf(s4) | ((unsigned)f2bf(s5)<<16);
        v.w = (unsigned)f2bf(s6) | ((unsigned)f2bf(s7)<<16);
      } else {
        v = *(const u4*)(ctx0bf + row*512 + e0);
      }
      int dst = op*32768 + row*512 + ((kc*16) ^ ((row&7)<<4));
      *(u4*)((char*)Ash + dst) = v;
    }
    __syncthreads();
    #pragma unroll 2
    for(int ktl=0; ktl<256; ktl+=32){
      s8v av[2][4];
      #pragma unroll
      for(int op=0;op<2;op++)
        #pragma unroll
        for(int mi=0;mi<4;mi++)
          av[op][mi] = *(const s8v*)((const char*)Ash + op*32768 + (mi*16+lr)*512 + ((ktl*2 + lg*16) ^ swz));
      int ki = kp*8 + (ktl>>5);
      const unsigned short* wb = Wp + (long)rgbase*8192 + ki*512 + lane*8;
      #pragma unroll
      for(int u=0;u<6;u++){
        s8v bv = *(const s8v*)(wb + (long)u*8192);
        #pragma unroll
        for(int mi=0;mi<4;mi++)
          acc2[u][mi] = __builtin_amdgcn_mfma_f32_16x16x32_bf16(av[u&1][mi], bv, acc2[u][mi], 0,0,0);
      }
    }
    __syncthreads();
  }

  int d = blk*64 + w*16 + lr;
  float bhr = b_hh[d], bhz = b_hh[512+d], bhn = b_hh[1024+d];
  #pragma unroll
  for(int mi=0;mi<4;mi++){
    #pragma unroll
    for(int r=0;r<4;r++){
      int b = mi*16 + lg*4 + r;
      const float* ge = gi_emb + (long)(t*64+b)*1536;
      float g0 = __builtin_nontemporal_load(ge + d);
      float g1 = __builtin_nontemporal_load(ge + 512 + d);
      float g2 = __builtin_nontemporal_load(ge + 1024 + d);
      float rr = sigmoidf_(g0 + bhr + acc2[0][mi][r] + acc2[1][mi][r]);
      float zz = sigmoidf_(g1 + bhz + acc2[2][mi][r] + acc2[3][mi][r]);
      float nn = tanhf_(  g2       + acc2[4][mi][r] + rr*(acc2[5][mi][r] + bhn));
      float hp = hrow_in[b*512 + d];
      float hv = (1.f-zz)*nn + zz*hp;
      hrow_out[b*512+d] = hv;
      unsigned short hb = f2bf(hv);
      h0bf_all[(long)(t*64+b)*512 + d] = hb;
      HS[b*72 + w*16 + lr] = hb;
      if(t==T_STEPS-1) outp[O_HID + b*512 + d] = hv;
    }
  }
  // finish covl of step t-1
  if(blk==0 && t>0 && tid<64){
    float s = covl_part[tid] + covl_part[64+tid] + covl_part[128+tid] + covl_part[192+tid];
    outp[O_COVL + (t-1)*64 + tid] = s;
  }
  __syncthreads();
  // q-partials over this block's 64 k-dims: qpart[blk][b][n]
  #pragma unroll
  for(int i=0;i<8;i++){
    f4 accq[4];
    #pragma unroll
    for(int mi=0;mi<4;mi++) accq[mi]=(f4)0.f;
    #pragma unroll
    for(int kf=0;kf<2;kf++){
      s8v bv = *(const s8v*)(WqP + ((((long)blk*32 + (w*8+i))*2 + kf)*64 + lane)*8);
      #pragma unroll
      for(int mi=0;mi<4;mi++){
        s8v av = *(const s8v*)(HS + (mi*16+lr)*72 + kf*32 + lg*8);
        accq[mi] = __builtin_amdgcn_mfma_f32_16x16x32_bf16(av, bv, accq[mi], 0,0,0);
      }
    }
    int n = w*128 + i*16 + lr;
    #pragma unroll
    for(int mi=0;mi<4;mi++)
      #pragma unroll
      for(int r=0;r<4;r++)
        qpart[(long)blk*32768 + (long)(mi*16+lg*4+r)*512 + n] = accq[mi][r];
  }
}

// ---------------- energy: wave-per-(b,s), nt-streamed pre ----------------
__global__ __launch_bounds__(512) void k_energy(
  const unsigned short* __restrict__ pre, const float* __restrict__ qpart,
  const float* __restrict__ q_g, const float* __restrict__ cov,
  const float* __restrict__ Wv, const float* __restrict__ Wcov,
  const float* __restrict__ padm, float* __restrict__ energy)
{
  __shared__ float q_sh[512], wv_sh[512], wc_sh[512], covL[104], padL[104];
  int cq = blockIdx.x, b = blockIdx.y; int c0 = cq*100;
  int tid = threadIdx.x, w = tid>>6, lane = tid&63;
  {
    float acc = q_g[b*512+tid];
    #pragma unroll
    for(int p=0;p<8;p++) acc += qpart[((long)p<<15) + b*512 + tid];
    q_sh[tid] = acc;
    wv_sh[tid] = Wv[tid]; wc_sh[tid] = Wcov[tid];
    if(tid<100){ covL[tid]=cov[b*400+c0+tid]; padL[tid]=padm[b*400+c0+tid]; }
  }
  __syncthreads();
  int i = w;
  u4 pf = {0,0,0,0};
  if(i<100) pf = ntld(pre + (((long)(b*400+c0+i))<<9) + lane*8);
  while(i<100){
    u4 cur = pf;
    int nx = i+8;
    if(nx<100) pf = ntld(pre + (((long)(b*400+c0+nx))<<9) + lane*8);
    float cv = covL[i];
    float part = 0.f;
    int a0 = lane*8;
    unsigned uu;
    #pragma unroll
    for(int q4=0;q4<4;q4++){
      uu = (q4==0)?cur.x:(q4==1)?cur.y:(q4==2)?cur.z:cur.w;
      int a = a0 + q4*2;
      part += wv_sh[a]  * tanhf_(bf2f((unsigned short)(uu&0xffffu)) + q_sh[a]   + cv*wc_sh[a]);
      part += wv_sh[a+1]* tanhf_(bf2f((unsigned short)(uu>>16))    + q_sh[a+1] + cv*wc_sh[a+1]);
    }
    #pragma unroll
    for(int off=32;off;off>>=1) part += __shfl_xor(part, off, 64);
    if(lane==0) energy[b*400+c0+i] = (padL[i]>0.5f) ? -1e18f : part;
    i = nx;
  }
}

// ---------------- softmax + coverage + context partials ----------------
__global__ __launch_bounds__(256) void k_smctx(
  const float* __restrict__ energy, float* __restrict__ cov,
  const unsigned short* __restrict__ ctxbf,
  unsigned short* __restrict__ P, float* __restrict__ covl_part,
  float* __restrict__ outp, int t)
{
  __shared__ float sm[400];
  __shared__ float red[256];
  __shared__ float pb[4][512];
  int sq = blockIdx.x, b = blockIdx.y, tid = threadIdx.x;
  int w = tid>>6, lane = tid&63;
  int c0 = sq*100;
  float v1 = energy[b*400+tid];
  bool has2 = tid<144;
  float v2 = has2 ? energy[b*400+256+tid] : -INFINITY;
  red[tid]=fmaxf(v1,v2); __syncthreads();
  for(int o=128;o;o>>=1){ if(tid<o) red[tid]=fmaxf(red[tid],red[tid+o]); __syncthreads(); }
  float mx = red[0]; __syncthreads();
  float p1=__expf(v1-mx), p2=has2?__expf(v2-mx):0.f;
  red[tid]=p1+p2; __syncthreads();
  for(int o=128;o;o>>=1){ if(tid<o) red[tid]+=red[tid+o]; __syncthreads(); }
  float inv = 1.f/red[0]; __syncthreads();
  sm[tid]=p1*inv; if(has2) sm[256+tid]=p2*inv;
  __syncthreads();
  // chunk-private coverage / gattn / covl partial
  float clp = 0.f;
  if(tid<100){
    int s = c0 + tid;
    float a = sm[s];
    float c = cov[b*400+s];
    clp = fminf(a,c);
    float nc = c + a;
    cov[b*400+s] = nc;
    outp[O_GATTN + (long)t*25600 + b*400 + s] = a;
    if(t==T_STEPS-1){ outp[O_ATTN_LAST + b*400 + s] = a; outp[O_COVF + b*400 + s] = nc; }
  }
  red[tid]=clp; __syncthreads();
  for(int o=128;o;o>>=1){ if(tid<o) red[tid]+=red[tid+o]; __syncthreads(); }
  if(tid==0) covl_part[sq*64+b]=red[0];
  // context partial over this chunk's 100 s (wave-per-row, nt)
  float acc8[8];
  #pragma unroll
  for(int j=0;j<8;j++) acc8[j]=0.f;
  int s = c0 + w;
  u4 pf = ntld(ctxbf + (((long)(b*400+s))<<9) + lane*8);
  #pragma unroll 1
  for(int j=0;j<25;j++){
    u4 cur = pf;
    int snx = s + 4;
    if(j<24) pf = ntld(ctxbf + (((long)(b*400+snx))<<9) + lane*8);
    float av = sm[s];
    acc8[0] = fmaf(av, bf2f((unsigned short)(cur.x&0xffffu)), acc8[0]);
    acc8[1] = fmaf(av, bf2f((unsigned short)(cur.x>>16)),     acc8[1]);
    acc8[2] = fmaf(av, bf2f((unsigned short)(cur.y&0xffffu)), acc8[2]);
    acc8[3] = fmaf(av, bf2f((unsigned short)(cur.y>>16)),     acc8[3]);
    acc8[4] = fmaf(av, bf2f((unsigned short)(cur.z&0xffffu)), acc8[4]);
    acc8[5] = fmaf(av, bf2f((unsigned short)(cur.z>>16)),     acc8[5]);
    acc8[6] = fmaf(av, bf2f((unsigned short)(cur.w&0xffffu)), acc8[6]);
    acc8[7] = fmaf(av, bf2f((unsigned short)(cur.w>>16)),     acc8[7]);
    s = snx;
  }
  #pragma unroll
  for(int j=0;j<8;j++) pb[w][lane*8+j]=acc8[j];
  __syncthreads();
  {
    int n = tid*2;
    float sA = pb[0][n]+pb[1][n]+pb[2][n]+pb[3][n];
    float sB = pb[0][n+1]+pb[1][n+1]+pb[2][n+1]+pb[3][n+1];
    unsigned short* pd = P + (((long)(t*4+sq))<<15) + b*512 + n;
    pd[0] = f2bf(sA); pd[1] = f2bf(sB);
  }
}

// ---------------- post-pass ----------------
__global__ void k_ctxsum(const unsigned short* __restrict__ P,
                         unsigned short* __restrict__ ctxA, float* __restrict__ outp){
  int o = blockIdx.x*256+threadIdx.x; if(o>=1638400) return;
  int t = o>>15; int rem = o&32767;
  float s = 0.f;
  #pragma unroll
  for(int p=0;p<4;p++) s += bf2f(P[(((long)(t*4+p))<<15) + rem]);
  ctxA[o] = f2bf(s);
  if(t==T_STEPS-1) outp[O_CTXF + rem] = s;
}

__global__ void k_covfin(const float* __restrict__ covl_part, float* __restrict__ outp){
  int b = threadIdx.x;
  if(b<64){
    float s = covl_part[b]+covl_part[64+b]+covl_part[128+b]+covl_part[192+b];
    outp[O_COVL + (T_STEPS-1)*64 + b] = s;
  }
}

__global__ __launch_bounds__(256) void k_pgen(
  const unsigned short* __restrict__ embU, const unsigned short* __restrict__ h0bf,
  const unsigned short* __restrict__ ctxA, const float* __restrict__ Wpg,
  const float* __restrict__ bpg, float* __restrict__ outp)
{
  int wid = threadIdx.x>>6, lane=threadIdx.x&63;
  int m = blockIdx.x*4 + wid;
  float acc=0.f;
  #pragma unroll
  for(int i=0;i<8;i++){
    int k = i*64+lane;
    acc = fmaf(bf2f(ctxA[(long)m*512+k]), Wpg[k], acc);
    acc = fmaf(bf2f(h0bf[(long)m*512+k]), Wpg[512+k], acc);
    acc = fmaf(bf2f(embU[(long)m*512+k]), Wpg[1024+k], acc);
  }
  #pragma unroll
  for(int off=32; off; off>>=1) acc += __shfl_xor(acc, off, 64);
  if(lane==0) outp[O_PG + m] = sigmoidf_(acc + bpg[0]);
}

__global__ void k_maxout(const float* __restrict__ RO, const float* __restrict__ ro_g,
                         float* __restrict__ outp){
  int o = blockIdx.x*256+threadIdx.x; if(o>=819200) return;
  int h = o & 255; int m = o>>8; int b = m & 63;
  float v0 = RO[(long)m*512 + 2*h]   + ro_g[b*512 + 2*h];
  float v1 = RO[(long)m*512 + 2*h+1] + ro_g[b*512 + 2*h+1];
  outp[O_GOUT + o] = fmaxf(v0,v1);
}

extern "C" void kernel_launch(void* const* d_in, const int* in_sizes, int n_in,
                              void* d_out, int out_size, void* d_ws, size_t ws_size,
                              hipStream_t stream)
{
  (void)in_sizes; (void)n_in; (void)out_size; (void)ws_size;
  const int*   y       = (const int*)d_in[0];
  const float* hidden  = (const float*)d_in[1];
  const float* context = (const float*)d_in[2];
  const float* padm    = (const float*)d_in[3];
  const float* init_att= (const float*)d_in[4];
  const float* coverage= (const float*)d_in[5];
  const float* gctx    = (const float*)d_in[6];
  const float* embW    = (const float*)d_in[7];
  const float* W_ih    = (const float*)d_in[8];
  const float* W_hh    = (const float*)d_in[9];
  const float* b_ih    = (const float*)d_in[10];
  const float* b_hh    = (const float*)d_in[11];
  const float* W_pre   = (const float*)d_in[12];
  const float* b_pre   = (const float*)d_in[13];
  const float* W_q     = (const float*)d_in[14];
  const float* W_v     = (const float*)d_in[15];
  const float* W_cov   = (const float*)d_in[16];
  const float* W_pg    = (const float*)d_in[17];
  const float* b_pg    = (const float*)d_in[18];
  const float* W_ro    = (const float*)d_in[19];
  const float* b_ro    = (const float*)d_in[20];
  float* out = (float*)d_out;

  char* wsb = (char*)d_ws;
  size_t off = 0;
  auto alloc = [&](size_t bytes)->char*{ char* p = wsb+off; off += (bytes+255)&~255UL; return p; };
  unsigned short* pre    = (unsigned short*)alloc(25600UL*512*2);
  unsigned short* ctxbf  = (unsigned short*)alloc(13107200UL*2);
  unsigned short* embU   = (unsigned short*)alloc(3200UL*512*2);
  unsigned short* wihbf  = (unsigned short*)alloc(1536UL*512*2);
  unsigned short* wpreT  = (unsigned short*)alloc(512UL*512*2);
  unsigned short* wroT   = (unsigned short*)alloc(512UL*2048*2);
  unsigned short* Wgru   = (unsigned short*)alloc(192UL*8192*2);
  unsigned short* WqP    = (unsigned short*)alloc(262144UL*2);
  float* gi_emb = (float*)alloc(3200UL*1536*4);
  float* RO     = (float*)alloc(3200UL*512*4);
  float* q_g    = (float*)alloc(64UL*512*4);
  float* ro_g   = (float*)alloc(64UL*512*4);
  float* hrow0  = (float*)alloc(64UL*512*4);
  float* hrow1  = (float*)alloc(64UL*512*4);
  float* gctxT  = (float*)alloc(512UL*64*4);
  unsigned short* h0bf = (unsigned short*)alloc(3200UL*512*2);
  unsigned short* h0bf_init = (unsigned short*)alloc(64UL*512*2);
  unsigned short* ctx0bf    = (unsigned short*)alloc(64UL*512*2);
  unsigned short* ctxA = (unsigned short*)alloc(3200UL*512*2);
  unsigned short* P    = (unsigned short*)alloc(50UL*4*64*512*2);   // context partials
  float* qpart  = (float*)alloc(8UL*64*512*4);
  float* covl_part = (float*)alloc(4UL*64*4);
  float* energy = (float*)alloc(64UL*400*4);
  float* cov    = (float*)alloc(64UL*400*4);

  // converts + init
  conv_ctx <<<dim3(51200),dim3(256),0,stream>>>(context, ctxbf);
  conv_emb <<<dim3(6400), dim3(256),0,stream>>>(y, embW, embU);
  conv_wihd<<<dim3(3072), dim3(256),0,stream>>>(W_ih, wihbf);
  conv_preT<<<dim3(1024), dim3(256),0,stream>>>(W_pre, wpreT);
  conv_roT <<<dim3(4096), dim3(256),0,stream>>>(W_ro, wroT);
  conv_wgru<<<dim3(6144), dim3(256),0,stream>>>(W_ih, W_hh, Wgru);
  conv_wq3 <<<dim3(1024), dim3(256),0,stream>>>(W_q, WqP);
  k_init   <<<dim3(485),  dim3(256),0,stream>>>(hidden, init_att, gctx, coverage,
                                                hrow0, h0bf_init, ctx0bf, gctxT, cov);

  // precompute GEMMs
  mfma_gemm<1,0><<<dim3(200,4),dim3(256),0,stream>>>(ctxbf,512, wpreT,512,0,  pre,   512, b_pre, 512);
  mfma_gemm<0,0><<<dim3(25,12),dim3(256),0,stream>>>(embU, 512, wihbf,512,0,  gi_emb,1536,b_ih, 512);
  mfma_gemm<0,0><<<dim3(25,4), dim3(256),0,stream>>>(embU, 512, wroT,2048,0,  RO,    512, b_ro, 512);
  small_gemm_kn<<<dim3(128),dim3(256),0,stream>>>(gctxT, W_q, 512, 512, nullptr, q_g);
  small_gemm_kn<<<dim3(128),dim3(256),0,stream>>>(gctxT, W_ro,1536, 512, nullptr, ro_g);

  // scan: 3 kernels/step
  for(int t=0; t<T_STEPS; t++){
    float* hin  = (t&1) ? hrow1 : hrow0;
    float* hout = (t&1) ? hrow0 : hrow1;
    const unsigned short* Pprev = t ? (P + ((long)(t-1)*4<<15)) : nullptr;
    const unsigned short* hprevbf = t ? (h0bf + (long)(t-1)*32768) : h0bf_init;
    k_gru_mfma<<<dim3(8),dim3(256),0,stream>>>(ctx0bf, Pprev, hprevbf, hin, hout,
                                               Wgru, WqP, gi_emb, b_hh, h0bf, qpart,
                                               covl_part, out, t);
    k_energy<<<dim3(4,64),dim3(512),0,stream>>>(pre, qpart, q_g, cov, W_v, W_cov, padm, energy);
    k_smctx <<<dim3(4,64),dim3(256),0,stream>>>(energy, cov, ctxbf, P, covl_part, out, t);
  }

  // post-pass
  k_ctxsum<<<dim3(6400),dim3(256),0,stream>>>(P, ctxA, out);
  mfma_gemm<0,1><<<dim3(25,4),dim3(256),0,stream>>>(h0bf,512, wroT,2048,512,  RO,512, nullptr, 512);
  mfma_gemm<0,1><<<dim3(25,4),dim3(256),0,stream>>>(ctxA,512, wroT,2048,1024, RO,512, nullptr, 512);
  k_covfin<<<dim3(1),  dim3(64), 0,stream>>>(covl_part, out);
  k_pgen  <<<dim3(800),dim3(256),0,stream>>>(embU, h0bf, ctxA, W_pg, b_pg, out);
  k_maxout<<<dim3(3200),dim3(256),0,stream>>>(RO, ro_g, out);
}